// Round 4
// baseline (305.840 us; speedup 1.0000x reference)
//
#include <hip/hip_runtime.h>
#include <hip/hip_bf16.h>

typedef unsigned short u16;
typedef unsigned int u32;
typedef float f32x4 __attribute__((ext_vector_type(4)));
typedef u16 u16x4 __attribute__((ext_vector_type(4)));
typedef u16 u16x8 __attribute__((ext_vector_type(8)));
typedef __bf16 bf16x8 __attribute__((ext_vector_type(8)));

#define OUT_DIM 4096
#define IN_DIM  4096
#define M_DIM   8192   // 4 * 2048

__device__ __forceinline__ u16 f2bf(float f) {
  u32 u = __builtin_bit_cast(u32, f);
  return (u16)((u + 0x7FFFu + ((u >> 16) & 1u)) >> 16);
}

// ---------------------------------------------------------------------------
// W build: codebook gather + sign unpack + 2-level inverse Haar + scale -> bf16
// ---------------------------------------------------------------------------
__global__ __launch_bounds__(256) void build_w_kernel(
    const float* __restrict__ codebook, const float* __restrict__ scales,
    const int* __restrict__ indices, const int* __restrict__ signs,
    u16* __restrict__ W) {
  __shared__ float c[IN_DIM];
  const int o   = blockIdx.x;
  const int tid = threadIdx.x;
  for (int g = tid; g < IN_DIM / 8; g += 256) {
    const int idx = indices[o * (IN_DIM / 8) + g];
    const int sp  = signs[o * (IN_DIM / 8) + g];
    f32x4 c0 = *(const f32x4*)&codebook[idx * 8];
    f32x4 c1 = *(const f32x4*)&codebook[idx * 8 + 4];
    float v[8] = {c0[0], c0[1], c0[2], c0[3], c1[0], c1[1], c1[2], c1[3]};
#pragma unroll
    for (int j = 0; j < 8; ++j)
      c[g * 8 + j] = ((sp >> j) & 1) ? v[j] : -v[j];
  }
  __syncthreads();
  const float scale = scales[o];
  const float S = 0.70710678118654752440f;
  for (int t = tid; t < IN_DIM / 4; t += 256) {
    float a   = c[t];
    float d1  = c[IN_DIM / 4 + t];
    float d2a = c[IN_DIM / 2 + 2 * t];
    float d2b = c[IN_DIM / 2 + 2 * t + 1];
    float e  = (a + d1) * S;
    float od = (a - d1) * S;
    u16x4 w;
    w[0] = f2bf((e  + d2a) * S * scale);
    w[1] = f2bf((e  - d2a) * S * scale);
    w[2] = f2bf((od + d2b) * S * scale);
    w[3] = f2bf((od - d2b) * S * scale);
    *(u16x4*)&W[(size_t)o * IN_DIM + 4 * t] = w;
  }
}

// ---------------------------------------------------------------------------
// X f32 -> bf16
// ---------------------------------------------------------------------------
__global__ __launch_bounds__(256) void cvt_x_kernel(
    const float* __restrict__ X, u16* __restrict__ Xb) {
  const int stride = gridDim.x * blockDim.x;
  const int n8 = (M_DIM * IN_DIM) / 8;
  for (int i = blockIdx.x * blockDim.x + threadIdx.x; i < n8; i += stride) {
    f32x4 a = *(const f32x4*)&X[(size_t)i * 8];
    f32x4 b = *(const f32x4*)&X[(size_t)i * 8 + 4];
    u16x8 r;
    r[0] = f2bf(a[0]); r[1] = f2bf(a[1]); r[2] = f2bf(a[2]); r[3] = f2bf(a[3]);
    r[4] = f2bf(b[0]); r[5] = f2bf(b[1]); r[6] = f2bf(b[2]); r[7] = f2bf(b[3]);
    *(u16x8*)&Xb[(size_t)i * 8] = r;
  }
}

// ---------------------------------------------------------------------------
// GEMM: C[M][N] f32 = A[M][K](bf16) x B[N][K](bf16, B^T layout).
// 256x256 tile, BK=32, 8 waves (2Mx4N), 4-deep LDS ring (128 KiB dynamic).
// R4: ONE phase per K-tile (32-MFMA cluster, 2 barriers/tile) to amortize the
// measured ~600cy fixed per-phase overhead. Full next-tile frag read-ahead.
// Gate: vmcnt(8) steady (retires exactly stage(t+1)), tails 4/0/none.
// ---------------------------------------------------------------------------
__global__ __launch_bounds__(512, 2) void gemm_bt_kernel(
    const u16* __restrict__ A,   // [M_DIM][K]
    const u16* __restrict__ B,   // [OUT_DIM][K]
    float*     __restrict__ C) { // [M_DIM][OUT_DIM]
  constexpr int K    = IN_DIM;
  constexpr int NT   = K / 32;     // 128 K-tiles
  constexpr int BUFB = 32768;      // bytes per ring buffer
  extern __shared__ char smem[];

  const int tid  = threadIdx.x;
  const int wave = tid >> 6;
  const int lane = tid & 63;

  // XCD-aware bijective swizzle (grid = 512, 512 % 8 == 0)
  const int swz = (blockIdx.x & 7) * 64 + (blockIdx.x >> 3);
  const int bm = (swz >> 4) * 256;   // 32 M-blocks
  const int bn = (swz & 15) * 256;   // 16 N-blocks

  const int wr  = (wave >> 2) * 128;  // wave M offset in tile
  const int wc  = (wave & 3) * 64;    // wave N offset in tile
  const int fr  = lane & 15;
  const int fkB = (lane >> 4) * 16;   // k-fragment byte offset in row

  // loop-invariant swizzled read offsets (involution: slot ^= (row>>1)&3)
  int offA[8], offB[4];
#pragma unroll
  for (int h = 0; h < 8; ++h) {
    int o = (wr + h * 16 + fr) * 64 + fkB;
    offA[h] = o ^ ((o >> 3) & 0x30);
  }
#pragma unroll
  for (int n = 0; n < 4; ++n) {
    int o = (wc + n * 16 + fr) * 64 + fkB;
    offB[n] = 16384 + (o ^ ((o >> 3) & 0x30));
  }

  // per-thread pre-swizzled global stage sources (inverse of read swizzle)
  const u16* srcA[2]; const u16* srcB[2];
#pragma unroll
  for (int i = 0; i < 2; ++i) {
    int d = i * 8192 + tid * 16;            // linear LDS dest byte
    int l = d ^ ((d >> 3) & 0x30);          // logical byte -> global column
    int row = d >> 6;
    srcA[i] = A + (size_t)(bm + row) * K + ((l & 63) >> 1);
    srcB[i] = B + (size_t)(bn + row) * K + ((l & 63) >> 1);
  }
  const int ldsW = wave * 1024;  // wave-uniform dest base (HW adds lane*16)

  auto stage = [&](int tt) {
    char* base = smem + (tt & 3) * BUFB + ldsW;
#pragma unroll
    for (int i = 0; i < 2; ++i) {
      __builtin_amdgcn_global_load_lds(
          (const __attribute__((address_space(1))) void*)(srcA[i] + tt * 32),
          (__attribute__((address_space(3))) void*)(base + i * 8192), 16, 0, 0);
      __builtin_amdgcn_global_load_lds(
          (const __attribute__((address_space(1))) void*)(srcB[i] + tt * 32),
          (__attribute__((address_space(3))) void*)(base + 16384 + i * 8192), 16, 0, 0);
    }
  };

  f32x4 acc[8][4] = {};
  bf16x8 aX[8], bX[4], aY[8], bY[4];

  // prologue: stage tiles 0,1,2 (12 loads); wait tile 0 (allow 8 newer)
  stage(0); stage(1); stage(2);
  asm volatile("s_waitcnt vmcnt(8)" ::: "memory");
  __builtin_amdgcn_s_barrier();
  {
    const char* buf0 = smem;
#pragma unroll
    for (int n = 0; n < 4; ++n) bX[n] = *(const bf16x8*)(buf0 + offB[n]);
#pragma unroll
    for (int m = 0; m < 8; ++m) aX[m] = *(const bf16x8*)(buf0 + offA[m]);
  }

  // one phase per K-tile: stage(t+3); gate; barrier; read t+1 frags; 32 MFMA(t)
  auto tileStep = [&](int t, bf16x8 (&cA)[8], bf16x8 (&cB)[4],
                      bf16x8 (&nA)[8], bf16x8 (&nB)[4]) {
    if (t + 3 < NT) stage(t + 3);
    // gate: ensure stage(t+1) retired before reading buf(t+1).
    if (t + 3 < NT)       asm volatile("s_waitcnt vmcnt(8)" ::: "memory");
    else if (t + 3 == NT) asm volatile("s_waitcnt vmcnt(4)" ::: "memory");
    else if (t + 2 == NT) asm volatile("s_waitcnt vmcnt(0)" ::: "memory");
    __builtin_amdgcn_s_barrier();
    if (t + 1 < NT) {
      const char* bufn = smem + ((t + 1) & 3) * BUFB;
#pragma unroll
      for (int n = 0; n < 4; ++n) nB[n] = *(const bf16x8*)(bufn + offB[n]);
#pragma unroll
      for (int m = 0; m < 8; ++m) nA[m] = *(const bf16x8*)(bufn + offA[m]);
    }
    __builtin_amdgcn_s_setprio(1);
#pragma unroll
    for (int m = 0; m < 8; ++m)
#pragma unroll
      for (int n = 0; n < 4; ++n)
        acc[m][n] = __builtin_amdgcn_mfma_f32_16x16x32_bf16(cA[m], cB[n], acc[m][n], 0, 0, 0);
    __builtin_amdgcn_s_setprio(0);
    __builtin_amdgcn_s_barrier();
  };

  for (int t = 0; t < NT; t += 2) {
    tileStep(t,     aX, bX, aY, bY);
    tileStep(t + 1, aY, bY, aX, bX);
  }

  // epilogue: C/D layout col=lane&15, row=(lane>>4)*4+j (m89-verified)
#pragma unroll
  for (int h = 0; h < 8; ++h)
#pragma unroll
    for (int n = 0; n < 4; ++n) {
      const int col = bn + wc + n * 16 + fr;
#pragma unroll
      for (int j = 0; j < 4; ++j) {
        const int row = bm + wr + h * 16 + (lane >> 4) * 4 + j;
        C[(size_t)row * OUT_DIM + col] = acc[h][n][j];
      }
    }
}

// ---------------------------------------------------------------------------
extern "C" void kernel_launch(void* const* d_in, const int* in_sizes, int n_in,
                              void* d_out, int out_size, void* d_ws, size_t ws_size,
                              hipStream_t stream) {
  const float* x        = (const float*)d_in[0];
  const float* codebook = (const float*)d_in[1];
  const float* scales   = (const float*)d_in[2];
  const int*   indices  = (const int*)d_in[3];
  const int*   signs    = (const int*)d_in[4];
  float* out = (float*)d_out;

  u16* W  = (u16*)d_ws;
  u16* Xb = (u16*)d_ws + (size_t)OUT_DIM * IN_DIM;

  (void)hipFuncSetAttribute((const void*)gemm_bt_kernel,
                            hipFuncAttributeMaxDynamicSharedMemorySize, 131072);

  build_w_kernel<<<OUT_DIM, 256, 0, stream>>>(codebook, scales, indices, signs, W);
  cvt_x_kernel<<<2048, 256, 0, stream>>>(x, Xb);
  gemm_bt_kernel<<<(M_DIM / 256) * (OUT_DIM / 256), 512, 131072, stream>>>(Xb, W, out);
}